// Round 13
// baseline (27.017 us; speedup 1.0000x reference)
//
#include <hip/hip_runtime.h>

#define T_DIM 1024
#define B_DIM 32
#define C_DIM 512
#define PROWS 128  // p-rows per block (A/B: 16->29.2, 32->28.4, 64->27.0, now 128)

typedef float f32x4 __attribute__((ext_vector_type(4)));

// R6-lineage skeleton, PROWS=128: one block = one batch b, 128 consecutive
// p-rows; grid = (8, 32) = 256 blocks = 1 per CU.
//   A: prefetch first 2 audio rows + labels; block-scan compaction
//   B: means of labeled video rows (2 rows per wave-iteration)
//   C: issue remaining 62 audio rows; 128-thread serial windowed product
//   D: mul + store burst
__global__ __launch_bounds__(256) void k_fused(const float* __restrict__ video,
                                               const float* __restrict__ audio,
                                               const int* __restrict__ labels,
                                               float* __restrict__ out) {
    int b     = blockIdx.y;
    int pBase = blockIdx.x * PROWS;
    int tid   = threadIdx.x;
    int lane  = tid & 63;
    int wave  = tid >> 6;
    __shared__ float vm[T_DIM];
    __shared__ int   pos[T_DIM];
    __shared__ int   waveTot[4];
    __shared__ float sscale[PROWS];

    // streaming geometry: thread handles rows k = 2*i + half, i = 0..63
    int half = tid >> 7;
    int c4   = tid & 127;
    const int rstep = 2 * B_DIM * (C_DIM / 4);
    int base0 = ((pBase + half) * B_DIM + b) * (C_DIM / 4) + c4;
    const f32x4* ain  = (const f32x4*)audio;
    f32x4*       aout = (f32x4*)out;

    // ---- phase A: prefetch first 2 audio rows + labels together ----
    f32x4 a[64];
    a[0] = ain[base0];
    a[1] = ain[base0 + rstep];
    int4 lv = *(const int4*)(labels + b * T_DIM + tid * 4);

    int p0 = tid * 4;
    int f0 = (lv.x == 1), f1 = (lv.y == 1), f2 = (lv.z == 1), f3 = (lv.w == 1);
    int cnt = f0 + f1 + f2 + f3;

    int incl = cnt;
    #pragma unroll
    for (int off = 1; off < 64; off <<= 1) {
        int n = __shfl_up(incl, off);
        if (lane >= off) incl += n;
    }
    if (lane == 63) waveTot[wave] = incl;
    __syncthreads();

    int waveOff = 0;
    for (int w = 0; w < wave; ++w) waveOff += waveTot[w];
    int t = waveTot[0] + waveTot[1] + waveTot[2] + waveTot[3];
    int r = waveOff + incl - cnt;

    if (f0) pos[r++] = p0 + 0;
    if (f1) pos[r++] = p0 + 1;
    if (f2) pos[r++] = p0 + 2;
    if (f3) pos[r++] = p0 + 3;
    __syncthreads();

    // ---- phase B: means of labeled rows, 2 rows per wave-iteration ----
    for (int rr = wave; rr < t; rr += 8) {
        const float* srcA = video + (size_t)pos[rr] * (B_DIM * C_DIM) + b * C_DIM;
        int rr2 = rr + 4;
        bool has2 = rr2 < t;
        const float* srcB = has2 ? video + (size_t)pos[rr2] * (B_DIM * C_DIM) + b * C_DIM
                                 : srcA;
        float4 va0 = *(const float4*)(srcA + lane * 4);
        float4 va1 = *(const float4*)(srcA + 256 + lane * 4);
        float4 vb0 = *(const float4*)(srcB + lane * 4);
        float4 vb1 = *(const float4*)(srcB + 256 + lane * 4);
        float sA = va0.x + va0.y + va0.z + va0.w + va1.x + va1.y + va1.z + va1.w;
        float sB = vb0.x + vb0.y + vb0.z + vb0.w + vb1.x + vb1.y + vb1.z + vb1.w;
        #pragma unroll
        for (int off = 32; off; off >>= 1) {
            sA += __shfl_xor(sA, off);
            sB += __shfl_xor(sB, off);
        }
        if (lane == 0) {
            vm[rr] = sA * (1.0f / C_DIM);
            if (has2) vm[rr2] = sB * (1.0f / C_DIM);
        }
    }
    __syncthreads();

    // ---- phase C: issue remaining 62 audio rows, then windowed product ----
    #pragma unroll
    for (int i = 2; i < 64; ++i)
        a[i] = ain[base0 + i * rstep];

    if (tid < PROWS) {
        int p  = pBase + tid;
        int lo = p - (T_DIM - t); if (lo < 0) lo = 0;
        int hi = p < (t - 1) ? p : (t - 1);
        float s = 1.0f;
        for (int m = lo; m <= hi; ++m) s *= vm[m];
        sscale[tid] = s;
    }
    __syncthreads();

    // ---- phase D: mul + store burst ----
    #pragma unroll
    for (int i = 0; i < 64; ++i) {
        float s = sscale[2 * i + half];
        aout[base0 + i * rstep] = a[i] * s;
    }
}

extern "C" void kernel_launch(void* const* d_in, const int* in_sizes, int n_in,
                              void* d_out, int out_size, void* d_ws, size_t ws_size,
                              hipStream_t stream) {
    const float* video  = (const float*)d_in[0];
    const float* audio  = (const float*)d_in[1];
    const int*   labels = (const int*)d_in[2];
    float* out = (float*)d_out;

    dim3 grid(T_DIM / PROWS, B_DIM);
    k_fused<<<grid, 256, 0, stream>>>(video, audio, labels, out);
}